// Round 24
// baseline (278.118 us; speedup 1.0000x reference)
//
#include <hip/hip_runtime.h>

// Complex MHA, B=4 S=1024 E=1024 H=16 DH=64.
// merged pack(fp32->fp16) -> GEMM1 (Karatsuba 3-mult, 128x128 block, 8 waves,
// 2 blk/CU) -> flash complex attention (swapped 32x32, 4-mult QK^T via
// Kr/Ki/-Ki) -> GEMM2 (Karatsuba, 64x64 blocks).

typedef _Float16 f16;
typedef _Float16 f16x8 __attribute__((ext_vector_type(8)));
typedef _Float16 f16x4 __attribute__((ext_vector_type(4)));
typedef float f32x4 __attribute__((ext_vector_type(4)));
typedef float f32x16 __attribute__((ext_vector_type(16)));

#define MFMA16(a, b, c) __builtin_amdgcn_mfma_f32_16x16x32_f16(a, b, c, 0, 0, 0)
#define MFMA32(a, b, c) __builtin_amdgcn_mfma_f32_32x32x16_f16(a, b, c, 0, 0, 0)

__device__ inline void load_lds16(const void* g, void* l) {
  __builtin_amdgcn_global_load_lds(
      (const __attribute__((address_space(1))) unsigned int*)g,
      (__attribute__((address_space(3))) unsigned int*)l, 16, 0, 0);
}

__device__ inline unsigned pkrtz(float a, float b) {
  auto t = __builtin_amdgcn_cvt_pkrtz(a, b);
  return __builtin_bit_cast(unsigned, t);
}

// ---------------- merged pack kernel (fp32 -> fp16) ---------------------------

__global__ void pack_all_kernel(const float* __restrict__ xr, const float* __restrict__ xi,
                                const float* __restrict__ wpr, const float* __restrict__ wpi,
                                const float* __restrict__ wor, const float* __restrict__ woi,
                                f16* __restrict__ XC, f16* __restrict__ WQKV,
                                f16* __restrict__ WOUT) {
  int i = blockIdx.x * 256 + threadIdx.x;
  if (i >= 4194304) return;
  const float* src;
  f16* dstp;
  float sgn = 1.f;
  if (i < 2097152) {
    int idx = i * 4;
    int m = idx >> 11, k = idx & 2047;
    src = (k < 1024) ? (xr + (size_t)m * 1024 + k) : (xi + (size_t)m * 1024 + k - 1024);
    dstp = XC + idx;
  } else if (i < 3670016) {
    int idx = (i - 2097152) * 4;
    int n = idx >> 11, k = idx & 2047;
    if (k < 1024) src = wpr + (size_t)n * 1024 + k;
    else { src = wpi + (size_t)n * 1024 + k - 1024; sgn = -1.f; }
    dstp = WQKV + idx;
  } else {
    int idx = (i - 3670016) * 4;
    int n = idx >> 11, k = idx & 2047;
    if (k < 1024) src = wor + (size_t)n * 1024 + k;
    else { src = woi + (size_t)n * 1024 + k - 1024; sgn = -1.f; }
    dstp = WOUT + idx;
  }
  float4 v = *(const float4*)src;
  f16x4 o = {(f16)(sgn * v.x), (f16)(sgn * v.y), (f16)(sgn * v.z), (f16)(sgn * v.w)};
  *(f16x4*)dstp = o;
}

struct GemmParams {
  f16 *QC, *KR, *KI, *KIN, *VCT;
  const float *bpr, *bpi;
  float* out;
  const float *bor, *boi;
  int out_complex;
};

// ---------------- GEMM1: Karatsuba, block 128x128, 8 waves (2M x 4N) ----------
// T1 = xr*wr ; U = xi*(-wi) ; T3 = (xr+xi)*(wr+wi). Re = T1+U ; Im = T3-T1+U.
// Wave tile 64x32; LDS 64 KB -> 2 blocks/CU (16 waves). Staging: 4 calls/tile
// (512 thr x 16B = one full 128-row half-tile per call).

__global__ __launch_bounds__(512, 2) void gemm1_kernel(const f16* __restrict__ A,
                                                       const f16* __restrict__ B,
                                                       GemmParams p) {
  const int KW = 2048;
  __shared__ alignas(16) f16 sAr[2][4096];
  __shared__ alignas(16) f16 sAi[2][4096];
  __shared__ alignas(16) f16 sBr[2][4096];
  __shared__ alignas(16) f16 sBu[2][4096];
  const int tid = threadIdx.x;
  const int w = tid >> 6, l = tid & 63;
  const int lr = l & 15, lk = l >> 4;
  // grid 768: xcd owns 3 n-tiles x 32 m-tiles (n-fastest for A reuse)
  const int lin = blockIdx.x;
  const int xcd = lin & 7, idx = lin >> 3;
  const int mt = idx / 3, ntl = idx % 3;
  const int tm0 = mt * 128;
  const int tn0 = (xcd * 3 + ntl) * 128;
  const int wm = (w >> 2) * 64, wn = (w & 3) * 32;

  // staging: 512 thr x 16B = 8KB = 128 rows x 64B per call; row = tid>>2,
  // pos = tid&3; logical chunk at pos pp of row r is pp ^ ((r>>1)&3).
  const int srow = tid >> 2;
  const int sk8 = ((tid & 3) ^ ((tid >> 3) & 3)) * 8;
  const f16* gAr = A + (size_t)(tm0 + srow) * KW + sk8;
  const f16* gAi = A + (size_t)(tm0 + srow) * KW + 1024 + sk8;
  const f16* gBr = B + (size_t)(tn0 + srow) * KW + sk8;
  const f16* gBu = B + (size_t)(tn0 + srow) * KW + 1024 + sk8;
  const int dst = w * 512;  // wave piece of each 4096-f16 region

#define STG(buf, k0) do {                              \
    load_lds16(gAr + (size_t)(k0), &sAr[buf][dst]);    \
    load_lds16(gAi + (size_t)(k0), &sAi[buf][dst]);    \
    load_lds16(gBr + (size_t)(k0), &sBr[buf][dst]);    \
    load_lds16(gBu + (size_t)(k0), &sBu[buf][dst]);    \
  } while (0)

  f32x4 a1[4][2] = {};
  f32x4 aU[4][2] = {};
  f32x4 a3[4][2] = {};

  STG(0, 0);
  asm volatile("s_waitcnt vmcnt(0)" ::: "memory");
  __syncthreads();

  const int ca = (lk ^ ((lr >> 1) & 3)) * 8;

  for (int t = 0; t < 32; ++t) {
    const int buf = t & 1;
    if (t < 31) STG(buf ^ 1, (t + 1) * 32);
    f16x8 ar[4], ai[4], br[2], bu[2];
#pragma unroll
    for (int mi = 0; mi < 4; ++mi) {
      ar[mi] = *(const f16x8*)&sAr[buf][(wm + mi * 16 + lr) * 32 + ca];
      ai[mi] = *(const f16x8*)&sAi[buf][(wm + mi * 16 + lr) * 32 + ca];
    }
#pragma unroll
    for (int nj = 0; nj < 2; ++nj) {
      br[nj] = *(const f16x8*)&sBr[buf][(wn + nj * 16 + lr) * 32 + ca];
      bu[nj] = *(const f16x8*)&sBu[buf][(wn + nj * 16 + lr) * 32 + ca];
    }
#pragma unroll
    for (int mi = 0; mi < 4; ++mi)
#pragma unroll
      for (int nj = 0; nj < 2; ++nj) {
        a1[mi][nj] = MFMA16(ar[mi], br[nj], a1[mi][nj]);
        aU[mi][nj] = MFMA16(ai[mi], bu[nj], aU[mi][nj]);
      }
#pragma unroll
    for (int mi = 0; mi < 4; ++mi) ar[mi] = ar[mi] + ai[mi];
#pragma unroll
    for (int nj = 0; nj < 2; ++nj) br[nj] = br[nj] - bu[nj];
#pragma unroll
    for (int mi = 0; mi < 4; ++mi)
#pragma unroll
      for (int nj = 0; nj < 2; ++nj)
        a3[mi][nj] = MFMA16(ar[mi], br[nj], a3[mi][nj]);
    asm volatile("s_waitcnt vmcnt(0)" ::: "memory");
    __syncthreads();
  }
#undef STG

#pragma unroll
  for (int mi = 0; mi < 4; ++mi)
#pragma unroll
    for (int nj = 0; nj < 2; ++nj) {
      int n = tn0 + wn + nj * 16 + lr;
      int m0 = tm0 + wm + mi * 16 + lk * 4;
      f32x4 re = a1[mi][nj] + aU[mi][nj];
      f32x4 im = a3[mi][nj] - a1[mi][nj] + aU[mi][nj];
      float br_ = p.bpr[n], bi_ = p.bpi[n];
      int part = n >> 10;
      int e = n & 1023, h = e >> 6, dd = e & 63;
      int bb = m0 >> 10, s0 = m0 & 1023;
      size_t bh = (size_t)bb * 16 + h;
      if (part == 0) {
#pragma unroll
        for (int r = 0; r < 4; ++r) {
          size_t o = (bh * 1024 + s0 + r) * 128;
          p.QC[o + dd] = (f16)((re[r] + br_) * 0.125f);
          p.QC[o + 64 + dd] = (f16)((im[r] + bi_) * 0.125f);
        }
      } else if (part == 1) {
#pragma unroll
        for (int r = 0; r < 4; ++r) {
          size_t o = (bh * 1024 + s0 + r) * 64;
          float vr = re[r] + br_, vi = im[r] + bi_;
          p.KR[o + dd] = (f16)vr;
          p.KI[o + dd] = (f16)vi;
          p.KIN[o + dd] = (f16)(-vi);
        }
      } else {
        f16x4 vvr, vvi;
#pragma unroll
        for (int r = 0; r < 4; ++r) { vvr[r] = (f16)(re[r] + br_); vvi[r] = (f16)(im[r] + bi_); }
        *(f16x4*)&p.VCT[((bh * 128 + dd)) * 1024 + s0] = vvr;
        *(f16x4*)&p.VCT[((bh * 128 + 64 + dd)) * 1024 + s0] = vvi;
      }
    }
}

// ---------------- GEMM2: Karatsuba complex, block 64x64, wave 32x32 -----------

__global__ __launch_bounds__(256, 4) void gemm2_kernel(const f16* __restrict__ A,
                                                       const f16* __restrict__ B,
                                                       GemmParams p) {
  const int KW = 2048;
  __shared__ alignas(16) f16 sAr[2][2048];
  __shared__ alignas(16) f16 sAi[2][2048];
  __shared__ alignas(16) f16 sBr[2][2048];
  __shared__ alignas(16) f16 sBu[2][2048];
  const int tid = threadIdx.x;
  const int w = tid >> 6, l = tid & 63;
  const int lr = l & 15, lk = l >> 4;
  const int lin = blockIdx.x;
  const int xcd = lin & 7, idx = lin >> 3;
  const int mt = idx >> 1, ntl = idx & 1;
  const int tm0 = mt * 64;
  const int tn0 = (xcd * 2 + ntl) * 64;
  const int wm = (w >> 1) * 32, wn = (w & 1) * 32;

  const int srow = tid >> 2;
  const int sk8 = ((tid & 3) ^ ((tid >> 3) & 3)) * 8;
  const f16* gAr = A + (size_t)(tm0 + srow) * KW + sk8;
  const f16* gAi = A + (size_t)(tm0 + srow) * KW + 1024 + sk8;
  const f16* gBr = B + (size_t)(tn0 + srow) * KW + sk8;
  const f16* gBu = B + (size_t)(tn0 + srow) * KW + 1024 + sk8;
  const int dst = w * 512;

#define STG2(buf, k0) do {                           \
    load_lds16(gAr + (size_t)(k0), &sAr[buf][dst]);  \
    load_lds16(gAi + (size_t)(k0), &sAi[buf][dst]);  \
    load_lds16(gBr + (size_t)(k0), &sBr[buf][dst]);  \
    load_lds16(gBu + (size_t)(k0), &sBu[buf][dst]);  \
  } while (0)

  f32x4 a1[2][2] = {};
  f32x4 aU[2][2] = {};
  f32x4 a3[2][2] = {};

  STG2(0, 0);
  asm volatile("s_waitcnt vmcnt(0)" ::: "memory");
  __syncthreads();

  const int ca = (lk ^ ((lr >> 1) & 3)) * 8;

  for (int t = 0; t < 32; ++t) {
    const int buf = t & 1;
    if (t < 31) STG2(buf ^ 1, (t + 1) * 32);
    f16x8 ar[2], ai[2], br[2], bu[2];
#pragma unroll
    for (int mi = 0; mi < 2; ++mi) {
      ar[mi] = *(const f16x8*)&sAr[buf][(wm + mi * 16 + lr) * 32 + ca];
      ai[mi] = *(const f16x8*)&sAi[buf][(wm + mi * 16 + lr) * 32 + ca];
    }
#pragma unroll
    for (int nj = 0; nj < 2; ++nj) {
      br[nj] = *(const f16x8*)&sBr[buf][(wn + nj * 16 + lr) * 32 + ca];
      bu[nj] = *(const f16x8*)&sBu[buf][(wn + nj * 16 + lr) * 32 + ca];
    }
#pragma unroll
    for (int mi = 0; mi < 2; ++mi)
#pragma unroll
      for (int nj = 0; nj < 2; ++nj) {
        a1[mi][nj] = MFMA16(ar[mi], br[nj], a1[mi][nj]);
        aU[mi][nj] = MFMA16(ai[mi], bu[nj], aU[mi][nj]);
      }
#pragma unroll
    for (int mi = 0; mi < 2; ++mi) ar[mi] = ar[mi] + ai[mi];
#pragma unroll
    for (int nj = 0; nj < 2; ++nj) br[nj] = br[nj] - bu[nj];
#pragma unroll
    for (int mi = 0; mi < 2; ++mi)
#pragma unroll
      for (int nj = 0; nj < 2; ++nj)
        a3[mi][nj] = MFMA16(ar[mi], br[nj], a3[mi][nj]);
    asm volatile("s_waitcnt vmcnt(0)" ::: "memory");
    __syncthreads();
  }
#undef STG2

#pragma unroll
  for (int mi = 0; mi < 2; ++mi)
#pragma unroll
    for (int nj = 0; nj < 2; ++nj) {
      int n = tn0 + wn + nj * 16 + lr;
      int m0 = tm0 + wm + mi * 16 + lk * 4;
      f32x4 re = a1[mi][nj] + aU[mi][nj];
      f32x4 im = a3[mi][nj] - a1[mi][nj] + aU[mi][nj];
      float br_ = p.bor[n], bi_ = p.boi[n];
#pragma unroll
      for (int r = 0; r < 4; ++r) {
        size_t m = (size_t)(m0 + r);
        if (p.out_complex) {
          p.out[(m * 1024 + n) * 2] = re[r] + br_;
          p.out[(m * 1024 + n) * 2 + 1] = im[r] + bi_;
        } else {
          p.out[m * 1024 + n] = re[r] + br_;
        }
      }
    }
}

// ---------------- flash complex attention -------------------------------------
// grid = 512 (8 q-tiles/head, XCD-local), 4 waves, QBLK=128, KBLK=32.

__global__ __launch_bounds__(256, 2) void attn_kernel(const f16* __restrict__ QC,
                                                      const f16* __restrict__ KR,
                                                      const f16* __restrict__ KI,
                                                      const f16* __restrict__ KIN,
                                                      const f16* __restrict__ VCT,
                                                      f16* __restrict__ OC) {
  __shared__ alignas(16) f16 sKr[2][2048];
  __shared__ alignas(16) f16 sKi[2][2048];
  __shared__ alignas(16) f16 sKn[2][2048];
  __shared__ alignas(16) f16 sV[2][4096];
  const int tid = threadIdx.x;
  const int w = tid >> 6, l = tid & 63;
  const int lq = l & 31, hi = l >> 5;
  const int bid = blockIdx.x;
  const int xx = bid & 7, yy = bid >> 3;
  const int bh = xx + ((yy >> 3) << 3);
  const int qt = yy & 7;
  const int q0 = qt * 128 + w * 32;
  const f16* Qb = QC + (size_t)bh * 1024 * 128;
  const f16* KRb = KR + (size_t)bh * 1024 * 64;
  const f16* KIb = KI + (size_t)bh * 1024 * 64;
  const f16* KNb = KIN + (size_t)bh * 1024 * 64;
  const f16* Vb = VCT + (size_t)bh * 128 * 1024;

  f16x8 qr[4], qi[4];
#pragma unroll
  for (int ks = 0; ks < 4; ++ks) {
    qr[ks] = *(const f16x8*)&Qb[(size_t)(q0 + lq) * 128 + ks * 16 + hi * 8];
    qi[ks] = *(const f16x8*)&Qb[(size_t)(q0 + lq) * 128 + 64 + ks * 16 + hi * 8];
  }

  f32x16 accR[4] = {};
  f32x16 accI[4] = {};
  float m_r = -1e30f, l_r = 0.f, m_i = -1e30f, l_i = 0.f;

  const int srK = tid >> 3;
  const int cgK = (tid & 7) ^ (srK & 7);
  const f16* gKR = KRb + (size_t)srK * 64 + cgK * 8;
  const f16* gKI = KIb + (size_t)srK * 64 + cgK * 8;
  const f16* gKN = KNb + (size_t)srK * 64 + cgK * 8;
  const int sprow = tid >> 3;
  const int cV = (tid & 7) ^ (sprow & 7);
  const f16* gV = Vb + (size_t)(sprow * 2 + (cV >> 2)) * 1024 + (cV & 3) * 8;
  const int ldsW = w * 512;

#define STAGE(s, k0)                                                       \
  do {                                                                     \
    load_lds16(gKR + (size_t)(k0) * 64, &sKr[s][ldsW]);                    \
    load_lds16(gKI + (size_t)(k0) * 64, &sKi[s][ldsW]);                    \
    load_lds16(gKN + (size_t)(k0) * 64, &sKn[s][ldsW]);                    \
    load_lds16(gV + (size_t)(k0), &sV[s][ldsW]);                           \
    load_lds16(gV + (size_t)64 * 1024 + (size_t)(k0), &sV[s][2048 + ldsW]);\
  } while (0)

  STAGE(0, 0);
  asm volatile("s_waitcnt vmcnt(0)" ::: "memory");
  __syncthreads();
  int cur = 0;

  for (int t = 0; t < 32; ++t) {
    if (t < 31) STAGE(cur ^ 1, (t + 1) * 32);

    f32x16 sr = {}, si = {};
    __builtin_amdgcn_s_setprio(1);
#pragma unroll
    for (int ks = 0; ks < 4; ++ks) {
      int ch = (((ks * 2 + hi) ^ (lq & 7))) * 8;
      f16x8 kr = *(const f16x8*)&sKr[cur][lq * 64 + ch];
      f16x8 ki = *(const f16x8*)&sKi[cur][lq * 64 + ch];
      f16x8 kn = *(const f16x8*)&sKn[cur][lq * 64 + ch];
      sr = MFMA32(kr, qr[ks], sr);
      sr = MFMA32(kn, qi[ks], sr);
      si = MFMA32(ki, qr[ks], si);
      si = MFMA32(kr, qi[ks], si);
    }
    __builtin_amdgcn_s_setprio(0);

    f16x8 prf[2], pif[2];
#pragma unroll
    for (int part = 0; part < 2; ++part) {
      const f32x16& s = part ? si : sr;
      float& m = part ? m_i : m_r;
      float& lsum = part ? l_i : l_r;
      f32x16* acc = part ? accI : accR;
      float vm = s[0];
#pragma unroll
      for (int j = 1; j < 16; ++j) vm = fmaxf(vm, s[j]);
      vm = fmaxf(vm, __shfl_xor(vm, 32));
      if (__any(vm > m + 8.f)) {
        float mn = fmaxf(m, vm);
        float sc = __expf(m - mn);
        lsum *= sc;
#pragma unroll
        for (int a = 0; a < 4; ++a)
#pragma unroll
          for (int j = 0; j < 16; ++j) acc[a][j] *= sc;
        m = mn;
      }
      float p[16];
      float ls = 0.f;
#pragma unroll
      for (int j = 0; j < 16; ++j) { p[j] = __expf(s[j] - m); ls += p[j]; }
      lsum += ls;
      unsigned a0 = pkrtz(p[0], p[1]), b0 = pkrtz(p[4], p[5]);
      unsigned a1 = pkrtz(p[2], p[3]), b1 = pkrtz(p[6], p[7]);
      unsigned a2 = pkrtz(p[8], p[9]), b2 = pkrtz(p[12], p[13]);
      unsigned a3 = pkrtz(p[10], p[11]), b3 = pkrtz(p[14], p[15]);
      asm("v_permlane32_swap_b32 %0, %1" : "+v"(a0), "+v"(b0));
      asm("v_permlane32_swap_b32 %0, %1" : "+v"(a1), "+v"(b1));
      asm("v_permlane32_swap_b32 %0, %1" : "+v"(a2), "+v"(b2));
      asm("v_permlane32_swap_b32 %0, %1" : "+v"(a3), "+v"(b3));
      union { unsigned u[4]; f16x8 v; } f0, f1;
      f0.u[0] = a0; f0.u[1] = a1; f0.u[2] = b0; f0.u[3] = b1;
      f1.u[0] = a2; f1.u[1] = a3; f1.u[2] = b2; f1.u[3] = b3;
      if (part) { pif[0] = f0.v; pif[1] = f1.v; }
      else      { prf[0] = f0.v; prf[1] = f1.v; }
    }

    __builtin_amdgcn_s_setprio(1);
#pragma unroll
    for (int ft = 0; ft < 4; ++ft) {
#pragma unroll
      for (int ks = 0; ks < 2; ++ks) {
        int feat = ft * 32 + lq;
        int prow = feat >> 1;
        int swzc = (((feat & 1) * 4 + ks * 2 + hi) ^ (prow & 7));
        f16x8 vf = *(const f16x8*)&sV[cur][prow * 64 + swzc * 8];
        accR[ft] = MFMA32(vf, prf[ks], accR[ft]);
        accI[ft] = MFMA32(vf, pif[ks], accI[ft]);
      }
    }
    __builtin_amdgcn_s_setprio(0);

    asm volatile("s_waitcnt vmcnt(0)" ::: "memory");
    __syncthreads();
    cur ^= 1;
  }
#undef STAGE

  float lr_ = l_r + __shfl_xor(l_r, 32);
  float li_ = l_i + __shfl_xor(l_i, 32);
  float ilr = 1.f / lr_, ili = 1.f / li_;
  const int bb = bh >> 4, h = bh & 15;
  const int q = q0 + lq;
  f16* rowp = OC + ((size_t)bb * 1024 + q) * 2048 + h * 64;
#pragma unroll
  for (int tt = 0; tt < 2; ++tt) {
#pragma unroll
    for (int g = 0; g < 4; ++g) {
      int d0 = tt * 32 + g * 8 + hi * 4;
      f16x4 ov, oiv;
#pragma unroll
      for (int j = 0; j < 4; ++j) {
        int rg = g * 4 + j;
        float orv = accR[tt][rg] * ilr - accI[tt + 2][rg] * ili;
        float oivv = accR[tt + 2][rg] * ilr + accI[tt][rg] * ili;
        ov[j] = (f16)orv;
        oiv[j] = (f16)oivv;
      }
      *(f16x4*)(rowp + d0) = ov;
      *(f16x4*)(rowp + 1024 + d0) = oiv;
    }
  }
}

// ---------------- launcher ----------------------------------------------------

extern "C" void kernel_launch(void* const* d_in, const int* in_sizes, int n_in,
                              void* d_out, int out_size, void* d_ws, size_t ws_size,
                              hipStream_t stream) {
  const float* xr = (const float*)d_in[0];
  const float* xi = (const float*)d_in[1];
  const float* wpr = (const float*)d_in[2];
  const float* wpi = (const float*)d_in[3];
  const float* bpr = (const float*)d_in[4];
  const float* bpi = (const float*)d_in[5];
  const float* wor = (const float*)d_in[6];
  const float* woi = (const float*)d_in[7];
  const float* bor = (const float*)d_in[8];
  const float* boi = (const float*)d_in[9];

  f16* ws = (f16*)d_ws;
  f16* XC = ws;                       // 4096*2048
  f16* WQKV = XC + 8388608;           // 3072*2048
  f16* QC = WQKV + 6291456;           // 64*1024*128
  f16* KR = QC + 8388608;             // 64*1024*64
  f16* KI = KR + 4194304;
  f16* KIN = KI + 4194304;
  f16* VCT = KIN + 4194304;           // 64*128*1024
  f16* OC = VCT + 8388608;            // 4096*2048
  f16* WOUT = OC + 8388608;           // 1024*2048

  pack_all_kernel<<<16384, 256, 0, stream>>>(xr, xi, wpr, wpi, wor, woi, XC, WQKV, WOUT);

  GemmParams p1 = {};
  p1.QC = QC; p1.KR = KR; p1.KI = KI; p1.KIN = KIN; p1.VCT = VCT;
  p1.bpr = bpr; p1.bpi = bpi;
  // 8 XCD x (32 m-tiles x 3 n-tiles) of 128x128 = 768 blocks
  gemm1_kernel<<<768, 512, 0, stream>>>(XC, WQKV, p1);

  attn_kernel<<<512, 256, 0, stream>>>(QC, KR, KI, KIN, VCT, OC);

  GemmParams p2 = {};
  p2.out = (float*)d_out; p2.bor = bor; p2.boi = boi;
  p2.out_complex = (out_size == 8388608) ? 1 : 0;
  gemm2_kernel<<<1024, 256, 0, stream>>>(OC, WOUT, p2);
}

// Round 25
// 253.383 us; speedup vs baseline: 1.0976x; 1.0976x over previous
//
#include <hip/hip_runtime.h>

// Complex MHA, B=4 S=1024 E=1024 H=16 DH=64.  (Best configuration: R22)
// merged pack(fp32->fp16) -> GEMM1 (Karatsuba 3-mult complex, dbuf loop;
// epilogue: Q concat, Kr/Ki/-Ki, V^T) -> flash complex attention (swapped
// 32x32, 4-mult QK^T via Kr/Ki/-Ki, 4-mult PV) -> GEMM2 (Karatsuba).

typedef _Float16 f16;
typedef _Float16 f16x8 __attribute__((ext_vector_type(8)));
typedef _Float16 f16x4 __attribute__((ext_vector_type(4)));
typedef float f32x4 __attribute__((ext_vector_type(4)));
typedef float f32x16 __attribute__((ext_vector_type(16)));

#define MFMA16(a, b, c) __builtin_amdgcn_mfma_f32_16x16x32_f16(a, b, c, 0, 0, 0)
#define MFMA32(a, b, c) __builtin_amdgcn_mfma_f32_32x32x16_f16(a, b, c, 0, 0, 0)

__device__ inline void load_lds16(const void* g, void* l) {
  __builtin_amdgcn_global_load_lds(
      (const __attribute__((address_space(1))) unsigned int*)g,
      (__attribute__((address_space(3))) unsigned int*)l, 16, 0, 0);
}

__device__ inline unsigned pkrtz(float a, float b) {
  auto t = __builtin_amdgcn_cvt_pkrtz(a, b);
  return __builtin_bit_cast(unsigned, t);
}

// ---------------- merged pack kernel (fp32 -> fp16) ---------------------------

__global__ void pack_all_kernel(const float* __restrict__ xr, const float* __restrict__ xi,
                                const float* __restrict__ wpr, const float* __restrict__ wpi,
                                const float* __restrict__ wor, const float* __restrict__ woi,
                                f16* __restrict__ XC, f16* __restrict__ WQKV,
                                f16* __restrict__ WOUT) {
  int i = blockIdx.x * 256 + threadIdx.x;
  if (i >= 4194304) return;
  const float* src;
  f16* dstp;
  float sgn = 1.f;
  if (i < 2097152) {
    int idx = i * 4;
    int m = idx >> 11, k = idx & 2047;
    src = (k < 1024) ? (xr + (size_t)m * 1024 + k) : (xi + (size_t)m * 1024 + k - 1024);
    dstp = XC + idx;
  } else if (i < 3670016) {
    int idx = (i - 2097152) * 4;
    int n = idx >> 11, k = idx & 2047;
    if (k < 1024) src = wpr + (size_t)n * 1024 + k;
    else { src = wpi + (size_t)n * 1024 + k - 1024; sgn = -1.f; }
    dstp = WQKV + idx;
  } else {
    int idx = (i - 3670016) * 4;
    int n = idx >> 11, k = idx & 2047;
    if (k < 1024) src = wor + (size_t)n * 1024 + k;
    else { src = woi + (size_t)n * 1024 + k - 1024; sgn = -1.f; }
    dstp = WOUT + idx;
  }
  float4 v = *(const float4*)src;
  f16x4 o = {(f16)(sgn * v.x), (f16)(sgn * v.y), (f16)(sgn * v.z), (f16)(sgn * v.w)};
  *(f16x4*)dstp = o;
}

struct GemmParams {
  f16 *QC, *KR, *KI, *KIN, *VCT;
  const float *bpr, *bpi;
  float* out;
  const float *bor, *boi;
  int out_complex;
};

// ---------------- Karatsuba complex GEMM: block 128x64, wave 64x32 ------------
// T1 = xr*wr ; U = xi*(-wi) ; T3 = (xr+xi)*(wr+wi). Re = T1+U ; Im = T3-T1+U.

template <int MODE>
__global__ __launch_bounds__(256, 3) void gemm_kernel(const f16* __restrict__ A,
                                                      const f16* __restrict__ B,
                                                      GemmParams p, int ntPerXcd) {
  const int KW = 2048;
  __shared__ alignas(16) f16 sAr[2][4096];
  __shared__ alignas(16) f16 sAi[2][4096];
  __shared__ alignas(16) f16 sBr[2][2048];
  __shared__ alignas(16) f16 sBu[2][2048];
  const int tid = threadIdx.x;
  const int w = tid >> 6, l = tid & 63;
  const int lr = l & 15, lk = l >> 4;
  const int lin = blockIdx.x;
  const int xcd = lin & 7, idx = lin >> 3;
  const int mt = idx / ntPerXcd, ntl = idx % ntPerXcd;
  const int tm0 = mt * 128;
  const int tn0 = (xcd * ntPerXcd + ntl) * 64;
  const int wm = (w >> 1) * 64, wn = (w & 1) * 32;

  const int srow = tid >> 2;
  const int sk8 = ((tid & 3) ^ ((tid >> 3) & 3)) * 8;
  const f16* gAr = A + (size_t)(tm0 + srow) * KW + sk8;
  const f16* gAi = A + (size_t)(tm0 + srow) * KW + 1024 + sk8;
  const f16* gBr = B + (size_t)(tn0 + srow) * KW + sk8;
  const f16* gBu = B + (size_t)(tn0 + srow) * KW + 1024 + sk8;
  const int dst = w * 512;

#define STG(buf, k0) do {                                                  \
    load_lds16(gAr + (size_t)(k0), &sAr[buf][dst]);                        \
    load_lds16(gAr + (size_t)64 * KW + (size_t)(k0), &sAr[buf][2048 + dst]);\
    load_lds16(gAi + (size_t)(k0), &sAi[buf][dst]);                        \
    load_lds16(gAi + (size_t)64 * KW + (size_t)(k0), &sAi[buf][2048 + dst]);\
    load_lds16(gBr + (size_t)(k0), &sBr[buf][dst]);                        \
    load_lds16(gBu + (size_t)(k0), &sBu[buf][dst]);                        \
  } while (0)

  f32x4 a1[4][2] = {};
  f32x4 aU[4][2] = {};
  f32x4 a3[4][2] = {};

  STG(0, 0);
  asm volatile("s_waitcnt vmcnt(0)" ::: "memory");
  __syncthreads();

  const int ca = (lk ^ ((lr >> 1) & 3)) * 8;

  for (int t = 0; t < 32; ++t) {
    const int buf = t & 1;
    if (t < 31) STG(buf ^ 1, (t + 1) * 32);
    f16x8 ar[4], ai[4], br[2], bu[2];
#pragma unroll
    for (int mi = 0; mi < 4; ++mi) {
      ar[mi] = *(const f16x8*)&sAr[buf][(wm + mi * 16 + lr) * 32 + ca];
      ai[mi] = *(const f16x8*)&sAi[buf][(wm + mi * 16 + lr) * 32 + ca];
    }
#pragma unroll
    for (int nj = 0; nj < 2; ++nj) {
      br[nj] = *(const f16x8*)&sBr[buf][(wn + nj * 16 + lr) * 32 + ca];
      bu[nj] = *(const f16x8*)&sBu[buf][(wn + nj * 16 + lr) * 32 + ca];
    }
#pragma unroll
    for (int mi = 0; mi < 4; ++mi)
#pragma unroll
      for (int nj = 0; nj < 2; ++nj) {
        a1[mi][nj] = MFMA16(ar[mi], br[nj], a1[mi][nj]);
        aU[mi][nj] = MFMA16(ai[mi], bu[nj], aU[mi][nj]);
      }
#pragma unroll
    for (int mi = 0; mi < 4; ++mi) ar[mi] = ar[mi] + ai[mi];
#pragma unroll
    for (int nj = 0; nj < 2; ++nj) br[nj] = br[nj] - bu[nj];
#pragma unroll
    for (int mi = 0; mi < 4; ++mi)
#pragma unroll
      for (int nj = 0; nj < 2; ++nj)
        a3[mi][nj] = MFMA16(ar[mi], br[nj], a3[mi][nj]);
    asm volatile("s_waitcnt vmcnt(0)" ::: "memory");
    __syncthreads();
  }
#undef STG

#pragma unroll
  for (int mi = 0; mi < 4; ++mi)
#pragma unroll
    for (int nj = 0; nj < 2; ++nj) {
      int n = tn0 + wn + nj * 16 + lr;
      int m0 = tm0 + wm + mi * 16 + lk * 4;
      f32x4 re = a1[mi][nj] + aU[mi][nj];
      f32x4 im = a3[mi][nj] - a1[mi][nj] + aU[mi][nj];
      if constexpr (MODE == 0) {
        float br_ = p.bpr[n], bi_ = p.bpi[n];
        int part = n >> 10;
        int e = n & 1023, h = e >> 6, dd = e & 63;
        int bb = m0 >> 10, s0 = m0 & 1023;
        size_t bh = (size_t)bb * 16 + h;
        if (part == 0) {
#pragma unroll
          for (int r = 0; r < 4; ++r) {
            size_t o = (bh * 1024 + s0 + r) * 128;
            p.QC[o + dd] = (f16)((re[r] + br_) * 0.125f);
            p.QC[o + 64 + dd] = (f16)((im[r] + bi_) * 0.125f);
          }
        } else if (part == 1) {
#pragma unroll
          for (int r = 0; r < 4; ++r) {
            size_t o = (bh * 1024 + s0 + r) * 64;
            float vr = re[r] + br_, vi = im[r] + bi_;
            p.KR[o + dd] = (f16)vr;
            p.KI[o + dd] = (f16)vi;
            p.KIN[o + dd] = (f16)(-vi);
          }
        } else {
          f16x4 vvr, vvi;
#pragma unroll
          for (int r = 0; r < 4; ++r) { vvr[r] = (f16)(re[r] + br_); vvi[r] = (f16)(im[r] + bi_); }
          *(f16x4*)&p.VCT[((bh * 128 + dd)) * 1024 + s0] = vvr;
          *(f16x4*)&p.VCT[((bh * 128 + 64 + dd)) * 1024 + s0] = vvi;
        }
      } else {
        float br_ = p.bor[n], bi_ = p.boi[n];
#pragma unroll
        for (int r = 0; r < 4; ++r) {
          size_t m = (size_t)(m0 + r);
          if (p.out_complex) {
            p.out[(m * 1024 + n) * 2] = re[r] + br_;
            p.out[(m * 1024 + n) * 2 + 1] = im[r] + bi_;
          } else {
            p.out[m * 1024 + n] = re[r] + br_;
          }
        }
      }
    }
}

// ---------------- flash complex attention -------------------------------------
// grid = 512 (8 q-tiles/head, XCD-local), 4 waves, QBLK=128, KBLK=32.
// 4-mult QK^T via Kr/Ki/-Ki arrays; 4-mult PV; defer-max; dbuf staging.

__global__ __launch_bounds__(256, 2) void attn_kernel(const f16* __restrict__ QC,
                                                      const f16* __restrict__ KR,
                                                      const f16* __restrict__ KI,
                                                      const f16* __restrict__ KIN,
                                                      const f16* __restrict__ VCT,
                                                      f16* __restrict__ OC) {
  __shared__ alignas(16) f16 sKr[2][2048];
  __shared__ alignas(16) f16 sKi[2][2048];
  __shared__ alignas(16) f16 sKn[2][2048];
  __shared__ alignas(16) f16 sV[2][4096];
  const int tid = threadIdx.x;
  const int w = tid >> 6, l = tid & 63;
  const int lq = l & 31, hi = l >> 5;
  const int bid = blockIdx.x;
  const int xx = bid & 7, yy = bid >> 3;
  const int bh = xx + ((yy >> 3) << 3);
  const int qt = yy & 7;
  const int q0 = qt * 128 + w * 32;
  const f16* Qb = QC + (size_t)bh * 1024 * 128;
  const f16* KRb = KR + (size_t)bh * 1024 * 64;
  const f16* KIb = KI + (size_t)bh * 1024 * 64;
  const f16* KNb = KIN + (size_t)bh * 1024 * 64;
  const f16* Vb = VCT + (size_t)bh * 128 * 1024;

  f16x8 qr[4], qi[4];
#pragma unroll
  for (int ks = 0; ks < 4; ++ks) {
    qr[ks] = *(const f16x8*)&Qb[(size_t)(q0 + lq) * 128 + ks * 16 + hi * 8];
    qi[ks] = *(const f16x8*)&Qb[(size_t)(q0 + lq) * 128 + 64 + ks * 16 + hi * 8];
  }

  f32x16 accR[4] = {};
  f32x16 accI[4] = {};
  float m_r = -1e30f, l_r = 0.f, m_i = -1e30f, l_i = 0.f;

  const int srK = tid >> 3;
  const int cgK = (tid & 7) ^ (srK & 7);
  const f16* gKR = KRb + (size_t)srK * 64 + cgK * 8;
  const f16* gKI = KIb + (size_t)srK * 64 + cgK * 8;
  const f16* gKN = KNb + (size_t)srK * 64 + cgK * 8;
  const int sprow = tid >> 3;
  const int cV = (tid & 7) ^ (sprow & 7);
  const f16* gV = Vb + (size_t)(sprow * 2 + (cV >> 2)) * 1024 + (cV & 3) * 8;
  const int ldsW = w * 512;

#define STAGE(s, k0)                                                       \
  do {                                                                     \
    load_lds16(gKR + (size_t)(k0) * 64, &sKr[s][ldsW]);                    \
    load_lds16(gKI + (size_t)(k0) * 64, &sKi[s][ldsW]);                    \
    load_lds16(gKN + (size_t)(k0) * 64, &sKn[s][ldsW]);                    \
    load_lds16(gV + (size_t)(k0), &sV[s][ldsW]);                           \
    load_lds16(gV + (size_t)64 * 1024 + (size_t)(k0), &sV[s][2048 + ldsW]);\
  } while (0)

  STAGE(0, 0);
  asm volatile("s_waitcnt vmcnt(0)" ::: "memory");
  __syncthreads();
  int cur = 0;

  for (int t = 0; t < 32; ++t) {
    if (t < 31) STAGE(cur ^ 1, (t + 1) * 32);

    f32x16 sr = {}, si = {};
    __builtin_amdgcn_s_setprio(1);
#pragma unroll
    for (int ks = 0; ks < 4; ++ks) {
      int ch = (((ks * 2 + hi) ^ (lq & 7))) * 8;
      f16x8 kr = *(const f16x8*)&sKr[cur][lq * 64 + ch];
      f16x8 ki = *(const f16x8*)&sKi[cur][lq * 64 + ch];
      f16x8 kn = *(const f16x8*)&sKn[cur][lq * 64 + ch];
      sr = MFMA32(kr, qr[ks], sr);
      sr = MFMA32(kn, qi[ks], sr);
      si = MFMA32(ki, qr[ks], si);
      si = MFMA32(kr, qi[ks], si);
    }
    __builtin_amdgcn_s_setprio(0);

    f16x8 prf[2], pif[2];
#pragma unroll
    for (int part = 0; part < 2; ++part) {
      const f32x16& s = part ? si : sr;
      float& m = part ? m_i : m_r;
      float& lsum = part ? l_i : l_r;
      f32x16* acc = part ? accI : accR;
      float vm = s[0];
#pragma unroll
      for (int j = 1; j < 16; ++j) vm = fmaxf(vm, s[j]);
      vm = fmaxf(vm, __shfl_xor(vm, 32));
      if (__any(vm > m + 8.f)) {
        float mn = fmaxf(m, vm);
        float sc = __expf(m - mn);
        lsum *= sc;
#pragma unroll
        for (int a = 0; a < 4; ++a)
#pragma unroll
          for (int j = 0; j < 16; ++j) acc[a][j] *= sc;
        m = mn;
      }
      float p[16];
      float ls = 0.f;
#pragma unroll
      for (int j = 0; j < 16; ++j) { p[j] = __expf(s[j] - m); ls += p[j]; }
      lsum += ls;
      unsigned a0 = pkrtz(p[0], p[1]), b0 = pkrtz(p[4], p[5]);
      unsigned a1 = pkrtz(p[2], p[3]), b1 = pkrtz(p[6], p[7]);
      unsigned a2 = pkrtz(p[8], p[9]), b2 = pkrtz(p[12], p[13]);
      unsigned a3 = pkrtz(p[10], p[11]), b3 = pkrtz(p[14], p[15]);
      asm("v_permlane32_swap_b32 %0, %1" : "+v"(a0), "+v"(b0));
      asm("v_permlane32_swap_b32 %0, %1" : "+v"(a1), "+v"(b1));
      asm("v_permlane32_swap_b32 %0, %1" : "+v"(a2), "+v"(b2));
      asm("v_permlane32_swap_b32 %0, %1" : "+v"(a3), "+v"(b3));
      union { unsigned u[4]; f16x8 v; } f0, f1;
      f0.u[0] = a0; f0.u[1] = a1; f0.u[2] = b0; f0.u[3] = b1;
      f1.u[0] = a2; f1.u[1] = a3; f1.u[2] = b2; f1.u[3] = b3;
      if (part) { pif[0] = f0.v; pif[1] = f1.v; }
      else      { prf[0] = f0.v; prf[1] = f1.v; }
    }

    __builtin_amdgcn_s_setprio(1);
#pragma unroll
    for (int ft = 0; ft < 4; ++ft) {
#pragma unroll
      for (int ks = 0; ks < 2; ++ks) {
        int feat = ft * 32 + lq;
        int prow = feat >> 1;
        int swzc = (((feat & 1) * 4 + ks * 2 + hi) ^ (prow & 7));
        f16x8 vf = *(const f16x8*)&sV[cur][prow * 64 + swzc * 8];
        accR[ft] = MFMA32(vf, prf[ks], accR[ft]);
        accI[ft] = MFMA32(vf, pif[ks], accI[ft]);
      }
    }
    __builtin_amdgcn_s_setprio(0);

    asm volatile("s_waitcnt vmcnt(0)" ::: "memory");
    __syncthreads();
    cur ^= 1;
  }
#undef STAGE

  float lr_ = l_r + __shfl_xor(l_r, 32);
  float li_ = l_i + __shfl_xor(l_i, 32);
  float ilr = 1.f / lr_, ili = 1.f / li_;
  const int bb = bh >> 4, h = bh & 15;
  const int q = q0 + lq;
  f16* rowp = OC + ((size_t)bb * 1024 + q) * 2048 + h * 64;
#pragma unroll
  for (int tt = 0; tt < 2; ++tt) {
#pragma unroll
    for (int g = 0; g < 4; ++g) {
      int d0 = tt * 32 + g * 8 + hi * 4;
      f16x4 ov, oiv;
#pragma unroll
      for (int j = 0; j < 4; ++j) {
        int rg = g * 4 + j;
        float orv = accR[tt][rg] * ilr - accI[tt + 2][rg] * ili;
        float oivv = accR[tt + 2][rg] * ilr + accI[tt][rg] * ili;
        ov[j] = (f16)orv;
        oiv[j] = (f16)oivv;
      }
      *(f16x4*)(rowp + d0) = ov;
      *(f16x4*)(rowp + 1024 + d0) = oiv;
    }
  }
}

// ---------------- launcher ----------------------------------------------------

extern "C" void kernel_launch(void* const* d_in, const int* in_sizes, int n_in,
                              void* d_out, int out_size, void* d_ws, size_t ws_size,
                              hipStream_t stream) {
  const float* xr = (const float*)d_in[0];
  const float* xi = (const float*)d_in[1];
  const float* wpr = (const float*)d_in[2];
  const float* wpi = (const float*)d_in[3];
  const float* bpr = (const float*)d_in[4];
  const float* bpi = (const float*)d_in[5];
  const float* wor = (const float*)d_in[6];
  const float* woi = (const float*)d_in[7];
  const float* bor = (const float*)d_in[8];
  const float* boi = (const float*)d_in[9];

  f16* ws = (f16*)d_ws;
  f16* XC = ws;                       // 4096*2048
  f16* WQKV = XC + 8388608;           // 3072*2048
  f16* QC = WQKV + 6291456;           // 64*1024*128
  f16* KR = QC + 8388608;             // 64*1024*64
  f16* KI = KR + 4194304;
  f16* KIN = KI + 4194304;
  f16* VCT = KIN + 4194304;           // 64*128*1024
  f16* OC = VCT + 8388608;            // 4096*2048
  f16* WOUT = OC + 8388608;           // 1024*2048

  pack_all_kernel<<<16384, 256, 0, stream>>>(xr, xi, wpr, wpi, wor, woi, XC, WQKV, WOUT);

  GemmParams p1 = {};
  p1.QC = QC; p1.KR = KR; p1.KI = KI; p1.KIN = KIN; p1.VCT = VCT;
  p1.bpr = bpr; p1.bpi = bpi;
  gemm_kernel<0><<<1536, 256, 0, stream>>>(XC, WQKV, p1, 6);

  attn_kernel<<<512, 256, 0, stream>>>(QC, KR, KI, KIN, VCT, OC);

  GemmParams p2 = {};
  p2.out = (float*)d_out; p2.bor = bor; p2.boi = boi;
  p2.out_complex = (out_size == 8388608) ? 1 : 0;
  gemm_kernel<1><<<512, 256, 0, stream>>>(OC, WOUT, p2, 2);
}